// Round 1
// baseline (1385.263 us; speedup 1.0000x reference)
//
#include <hip/hip_runtime.h>

// GlobalEdgeGnn on MI355X (gfx950).
// N=50000 nodes, E=500000 undirected edges (1M directed), D=64, H=128, 3 conv layers.
// Pipeline: CSR build -> init node means -> 3x (MFMA MLP over directed edges -> mean agg)
//           -> symmetric edge MLP (both directions in one wave-tile) + side loss.
// bf16 MFMA (16x16x32), fp32 residual master. Messages materialized bf16 (round-0 2-pass).

#define NN 50000
#define NE 500000
#define DE 1000000   // 2E directed
#define DD 64
#define HH 128

typedef __attribute__((ext_vector_type(8))) __bf16 bfrag;
typedef __attribute__((ext_vector_type(8))) short  svec8;
typedef __attribute__((ext_vector_type(4))) float  f32x4;

__device__ __forceinline__ unsigned short f2bf(float f){
  unsigned u = __builtin_bit_cast(unsigned, f);
  u += 0x7fffu + ((u >> 16) & 1u);          // RNE
  return (unsigned short)(u >> 16);
}
__device__ __forceinline__ float bf2f(unsigned short s){
  return __builtin_bit_cast(float, ((unsigned)s) << 16);
}
#define MFMA __builtin_amdgcn_mfma_f32_16x16x32_bf16

// ---------------- CSR build ----------------
__global__ void k_hist(const int* __restrict__ ei, int* __restrict__ cnt){
  int e = blockIdx.x*256 + threadIdx.x;
  if (e >= DE) return;
  int dst = (e < NE) ? ei[NE + e] : ei[e - NE];   // bi_dst
  atomicAdd(&cnt[dst], 1);
}

__global__ void k_scan(const int* __restrict__ cnt, int* __restrict__ off,
                       int* __restrict__ cur, float* __restrict__ dinv){
  __shared__ int sbuf[1024];
  int tid = threadIdx.x;
  int carry = 0;
  for (int base = 0; base < NN; base += 1024){
    int i = base + tid;
    int v = (i < NN) ? cnt[i] : 0;
    __syncthreads();               // protect prior iteration's sbuf reads
    sbuf[tid] = v;
    __syncthreads();
    for (int s = 1; s < 1024; s <<= 1){
      int t = (tid >= s) ? sbuf[tid - s] : 0;
      __syncthreads();
      sbuf[tid] += t;
      __syncthreads();
    }
    if (i < NN){
      int ex = carry + sbuf[tid] - v;   // exclusive
      off[i] = ex; cur[i] = ex;
      dinv[i] = 1.0f / (float)(v > 1 ? v : 1);
    }
    carry += sbuf[1023];
  }
  if (tid == 0) off[NN] = carry;   // == DE
}

__global__ void k_fill(const int* __restrict__ ei, int* __restrict__ cur,
                       int* __restrict__ nbr, int* __restrict__ dstA, int* __restrict__ eid){
  int e = blockIdx.x*256 + threadIdx.x;
  if (e >= DE) return;
  int s, d, id;
  if (e < NE){ s = ei[e];  d = ei[NE + e]; id = e;      }   // (src,dst)
  else       { s = ei[e];  d = ei[e - NE]; id = e - NE; }   // (dst,src)
  int pos = atomicAdd(&cur[d], 1);
  nbr[pos] = s; dstA[pos] = d; eid[pos] = id;
}

// ---------------- weight pack to MFMA B-fragment order (bf16) ----------------
// layout per matrix: frag f = kb*(NO/16)+nb ; elem = f*512 + lane*8 + i
// value = W[kb*32 + (lane>>4)*8 + i][nb*16 + (lane&15)]
__global__ void k_pack(const float* __restrict__ nw1, const float* __restrict__ nw2,
                       const float* __restrict__ ew1, const float* __restrict__ ew2,
                       unsigned short* __restrict__ wp){
  int t = blockIdx.x*256 + threadIdx.x;
  if (t >= 98304) return;
  const float* src; int NO, p, base;
  if (t < 49152)      { int l = t/16384;            src = nw1 + l*16384; NO=128; p = t - l*16384;      base = t - p; }
  else if (t < 73728) { int q = t-49152; int l=q/8192; src = nw2 + l*8192; NO=64; p = q - l*8192;      base = t - p; }
  else if (t < 90112) {                              src = ew1;           NO=128; p = t - 73728;       base = 73728; }
  else                {                              src = ew2;           NO=64;  p = t - 90112;       base = 90112; }
  int f = p >> 9, r = p & 511, lane = r >> 3, i = r & 7;
  int NB = NO >> 4, kb = f / NB, nb = f - kb*NB;
  int k = kb*32 + ((lane >> 4) << 3) + i;
  int c = nb*16 + (lane & 15);
  wp[base + p] = f2bf(src[k*NO + c]);
}

// ---------------- node init: x = mean of incident edge features ----------------
__global__ void k_init(const float* __restrict__ ef, const int* __restrict__ off,
                       const int* __restrict__ eid, const float* __restrict__ dinv,
                       float* __restrict__ x, unsigned short* __restrict__ xbf){
  int n = blockIdx.x*4 + (threadIdx.x >> 6);
  int lane = threadIdx.x & 63;
  if (n >= NN) return;
  int s0 = off[n], s1 = off[n+1];
  float acc = 0.f;
  for (int s = s0; s < s1; s++) acc += ef[eid[s]*64 + lane];
  float v = acc * dinv[n];
  x[n*64 + lane] = v;
  xbf[n*64 + lane] = f2bf(v);
}

// ---------------- NodeConv MLP over directed edges (CSR order) ----------------
// wave tile = 32 rows (2 x 16). GEMM1: [32,128]x[128,128] relu; GEMM2: [32,128]x[128,64] relu.
// A gathered from xbf (L2-resident). W1 in LDS (packed frags). h via XOR-swizzled LDS.
__global__ __launch_bounds__(256,2) void k_conv(
    const unsigned short* __restrict__ xbf,
    const int* __restrict__ cdst, const int* __restrict__ cnbr,
    const unsigned short* __restrict__ wp, int w1off, int w2off,
    const float* __restrict__ b1, const float* __restrict__ b2,
    unsigned short* __restrict__ mout)
{
  extern __shared__ char smem[];                 // 32KB w1 + 4*8KB h = 64KB
  short* w1s = (short*)smem;
  const svec8* w1g = (const svec8*)(wp + w1off);
  for (int i = threadIdx.x; i < 2048; i += 256) ((svec8*)w1s)[i] = w1g[i];
  __syncthreads();
  int lane = threadIdx.x & 63, wid = threadIdx.x >> 6;
  int tile = (blockIdx.x*4 + wid) * 32;
  if (tile >= DE) return;
  char* hw = smem + 32768 + wid*8192;
  int r16 = lane & 15, g = lane >> 4;

  f32x4 acc1[8][2];
  #pragma unroll
  for (int nb = 0; nb < 8; nb++){ acc1[nb][0] = (f32x4){0,0,0,0}; acc1[nb][1] = (f32x4){0,0,0,0}; }

  #pragma unroll
  for (int kb = 0; kb < 4; kb++){
    int k0 = kb*32 + g*8;
    const int* ns = (kb < 2) ? cdst : cnbr;      // cat[x_dst, x_src]
    int sa = tile + r16;       if (sa >= DE) sa = DE-1;
    int sb = tile + 16 + r16;  if (sb >= DE) sb = DE-1;
    bfrag a0 = __builtin_bit_cast(bfrag, *(const svec8*)(xbf + ns[sa]*64 + (k0 & 63)));
    bfrag a1 = __builtin_bit_cast(bfrag, *(const svec8*)(xbf + ns[sb]*64 + (k0 & 63)));
    #pragma unroll
    for (int nb = 0; nb < 8; nb++){
      bfrag b = __builtin_bit_cast(bfrag, ((const svec8*)w1s)[(kb*8+nb)*64 + lane]);
      acc1[nb][0] = MFMA(a0, b, acc1[nb][0], 0, 0, 0);
      acc1[nb][1] = MFMA(a1, b, acc1[nb][1], 0, 0, 0);
    }
  }
  // h (relu) -> swizzled LDS, row stride 256B, byte ^= (row&7)<<4
  #pragma unroll
  for (int nb = 0; nb < 8; nb++){
    float bias = b1[nb*16 + r16];
    #pragma unroll
    for (int rb = 0; rb < 2; rb++){
      #pragma unroll
      for (int j = 0; j < 4; j++){
        float v = acc1[nb][rb][j] + bias; v = v > 0.f ? v : 0.f;
        int row = rb*16 + g*4 + j;
        int byt = row*256 + (nb*16 + r16)*2;  byt ^= (row & 7) << 4;
        *(short*)(hw + byt) = (short)f2bf(v);
      }
    }
  }
  f32x4 acc2[4][2];
  #pragma unroll
  for (int nb = 0; nb < 4; nb++){ acc2[nb][0] = (f32x4){0,0,0,0}; acc2[nb][1] = (f32x4){0,0,0,0}; }
  const svec8* w2g = (const svec8*)(wp + w2off);
  #pragma unroll
  for (int kb = 0; kb < 4; kb++){
    bfrag a2[2];
    #pragma unroll
    for (int rb = 0; rb < 2; rb++){
      int row = rb*16 + r16;
      int byt = row*256 + (kb*32 + g*8)*2;  byt ^= (row & 7) << 4;
      a2[rb] = __builtin_bit_cast(bfrag, *(const svec8*)(hw + byt));
    }
    #pragma unroll
    for (int nb = 0; nb < 4; nb++){
      bfrag b = __builtin_bit_cast(bfrag, w2g[(kb*4+nb)*64 + lane]);
      acc2[nb][0] = MFMA(a2[0], b, acc2[nb][0], 0, 0, 0);
      acc2[nb][1] = MFMA(a2[1], b, acc2[nb][1], 0, 0, 0);
    }
  }
  #pragma unroll
  for (int nb = 0; nb < 4; nb++){
    float bias = b2[nb*16 + r16];
    #pragma unroll
    for (int rb = 0; rb < 2; rb++){
      #pragma unroll
      for (int j = 0; j < 4; j++){
        int slot = tile + rb*16 + g*4 + j;
        if (slot < DE){
          float v = acc2[nb][rb][j] + bias; v = v > 0.f ? v : 0.f;
          mout[slot*64 + nb*16 + r16] = f2bf(v);
        }
      }
    }
  }
}

// ---------------- aggregation: x += mean of messages (CSR-contiguous) ----------------
__global__ void k_agg(const unsigned short* __restrict__ m, const int* __restrict__ off,
                      const float* __restrict__ dinv, float* __restrict__ x,
                      unsigned short* __restrict__ xbf){
  int n = blockIdx.x*4 + (threadIdx.x >> 6);
  int lane = threadIdx.x & 63;
  if (n >= NN) return;
  int s0 = off[n], s1 = off[n+1];
  float acc = 0.f;
  for (int s = s0; s < s1; s++) acc += bf2f(m[s*64 + lane]);
  float v = x[n*64 + lane] + acc * dinv[n];
  x[n*64 + lane] = v;
  xbf[n*64 + lane] = f2bf(v);
}

// ---------------- symmetric edge MLP; both directions as the two row-blocks ----------------
__global__ __launch_bounds__(256,2) void k_edge(
    const unsigned short* __restrict__ xbf, const int* __restrict__ ei,
    const unsigned short* __restrict__ wp,
    const float* __restrict__ b1, const float* __restrict__ b2,
    float* __restrict__ outp, float* __restrict__ side)
{
  extern __shared__ char smem[];
  short* w1s = (short*)smem;
  const svec8* w1g = (const svec8*)(wp + 73728);
  for (int i = threadIdx.x; i < 2048; i += 256) ((svec8*)w1s)[i] = w1g[i];
  __syncthreads();
  int lane = threadIdx.x & 63, wid = threadIdx.x >> 6;
  int tile = (blockIdx.x*4 + wid) * 16;          // 16 undirected edges
  if (tile >= NE) return;
  char* hw = smem + 32768 + wid*8192;
  int r16 = lane & 15, g = lane >> 4;
  int el = tile + r16;
  int sn = ei[el], dn = ei[NE + el];

  f32x4 acc1[8][2];
  #pragma unroll
  for (int nb = 0; nb < 8; nb++){ acc1[nb][0] = (f32x4){0,0,0,0}; acc1[nb][1] = (f32x4){0,0,0,0}; }

  #pragma unroll
  for (int kb = 0; kb < 4; kb++){
    int k0 = kb*32 + g*8;
    int n0 = (kb < 2) ? sn : dn;                 // dir0 = cat[x_src, x_dst]
    int n1 = (kb < 2) ? dn : sn;                 // dir1 = cat[x_dst, x_src]
    bfrag a0 = __builtin_bit_cast(bfrag, *(const svec8*)(xbf + n0*64 + (k0 & 63)));
    bfrag a1 = __builtin_bit_cast(bfrag, *(const svec8*)(xbf + n1*64 + (k0 & 63)));
    #pragma unroll
    for (int nb = 0; nb < 8; nb++){
      bfrag b = __builtin_bit_cast(bfrag, ((const svec8*)w1s)[(kb*8+nb)*64 + lane]);
      acc1[nb][0] = MFMA(a0, b, acc1[nb][0], 0, 0, 0);
      acc1[nb][1] = MFMA(a1, b, acc1[nb][1], 0, 0, 0);
    }
  }
  #pragma unroll
  for (int nb = 0; nb < 8; nb++){
    float bias = b1[nb*16 + r16];
    #pragma unroll
    for (int rb = 0; rb < 2; rb++){
      #pragma unroll
      for (int j = 0; j < 4; j++){
        float v = acc1[nb][rb][j] + bias; v = v > 0.f ? v : 0.f;
        int row = rb*16 + g*4 + j;
        int byt = row*256 + (nb*16 + r16)*2;  byt ^= (row & 7) << 4;
        *(short*)(hw + byt) = (short)f2bf(v);
      }
    }
  }
  f32x4 acc2[4][2];
  #pragma unroll
  for (int nb = 0; nb < 4; nb++){ acc2[nb][0] = (f32x4){0,0,0,0}; acc2[nb][1] = (f32x4){0,0,0,0}; }
  const svec8* w2g = (const svec8*)(wp + 90112);
  #pragma unroll
  for (int kb = 0; kb < 4; kb++){
    bfrag a2[2];
    #pragma unroll
    for (int rb = 0; rb < 2; rb++){
      int row = rb*16 + r16;
      int byt = row*256 + (kb*32 + g*8)*2;  byt ^= (row & 7) << 4;
      a2[rb] = __builtin_bit_cast(bfrag, *(const svec8*)(hw + byt));
    }
    #pragma unroll
    for (int nb = 0; nb < 4; nb++){
      bfrag b = __builtin_bit_cast(bfrag, w2g[(kb*4+nb)*64 + lane]);
      acc2[nb][0] = MFMA(a2[0], b, acc2[nb][0], 0, 0, 0);   // e1
      acc2[nb][1] = MFMA(a2[1], b, acc2[nb][1], 0, 0, 0);   // e2
    }
  }
  float lsum = 0.f;
  #pragma unroll
  for (int nb = 0; nb < 4; nb++){
    float bias = b2[nb*16 + r16];
    #pragma unroll
    for (int j = 0; j < 4; j++){
      float v1 = acc2[nb][0][j] + bias;
      float v2 = acc2[nb][1][j] + bias;
      int e = tile + g*4 + j;
      outp[e*64 + nb*16 + r16] = 0.5f*(v1 + v2);
      float d = v1 - v2; lsum += d*d;
    }
  }
  for (int o2 = 32; o2 > 0; o2 >>= 1) lsum += __shfl_down(lsum, o2);
  if (lane == 0) atomicAdd(side, lsum);
}

__global__ void k_final(const float* __restrict__ side, float* __restrict__ outp){
  if (threadIdx.x == 0) outp[32000000] = side[0] * (1.0f / 32000000.0f);
}

// ---------------- launch ----------------
extern "C" void kernel_launch(void* const* d_in, const int* in_sizes, int n_in,
                              void* d_out, int out_size, void* d_ws, size_t ws_size,
                              hipStream_t stream)
{
  const float* ef  = (const float*)d_in[0];
  const int*   ei  = (const int*)  d_in[1];
  const float* nw1 = (const float*)d_in[2];
  const float* nb1 = (const float*)d_in[3];
  const float* nw2 = (const float*)d_in[4];
  const float* nb2 = (const float*)d_in[5];
  const float* ew1 = (const float*)d_in[6];
  const float* eb1 = (const float*)d_in[7];
  const float* ew2 = (const float*)d_in[8];
  const float* eb2 = (const float*)d_in[9];
  float* outp = (float*)d_out;

  char* ws = (char*)d_ws;
  size_t o = 0;
  auto alloc = [&](size_t b)->char*{ char* p = ws + o; o += (b + 255) & ~(size_t)255; return p; };
  int*   cnt  = (int*)  alloc((size_t)NN*4);
  int*   off  = (int*)  alloc((size_t)(NN+1)*4);
  int*   cur  = (int*)  alloc((size_t)NN*4);
  float* dinv = (float*)alloc((size_t)NN*4);
  int*   nbr  = (int*)  alloc((size_t)DE*4);
  int*   dstA = (int*)  alloc((size_t)DE*4);
  int*   eid  = (int*)  alloc((size_t)DE*4);
  float* x    = (float*)alloc((size_t)NN*64*4);
  unsigned short* xbf = (unsigned short*)alloc((size_t)NN*64*2);
  unsigned short* wp  = (unsigned short*)alloc((size_t)98304*2);
  float* side = (float*)alloc(256);
  unsigned short* mbf = (unsigned short*)alloc((size_t)DE*64*2);   // ~153 MB total ws

  hipMemsetAsync(cnt, 0, (size_t)NN*4, stream);
  hipMemsetAsync(side, 0, 4, stream);
  k_hist<<<(DE+255)/256, 256, 0, stream>>>(ei, cnt);
  k_scan<<<1, 1024, 0, stream>>>(cnt, off, cur, dinv);
  k_fill<<<(DE+255)/256, 256, 0, stream>>>(ei, cur, nbr, dstA, eid);
  k_pack<<<384, 256, 0, stream>>>(nw1, nw2, ew1, ew2, wp);
  k_init<<<NN/4, 256, 0, stream>>>(ef, off, eid, dinv, x, xbf);
  for (int l = 0; l < 3; l++){
    k_conv<<<DE/128 + 1, 256, 65536, stream>>>(xbf, dstA, nbr, wp,
                                               l*16384, 49152 + l*8192,
                                               nb1 + l*128, nb2 + l*64, mbf);
    k_agg<<<NN/4, 256, 0, stream>>>(mbf, off, dinv, x, xbf);
  }
  k_edge<<<NE/64 + 1, 256, 65536, stream>>>(xbf, ei, wp, eb1, eb2, outp, side);
  k_final<<<1, 64, 0, stream>>>(side, outp);
}